// Round 18
// baseline (383.292 us; speedup 1.0000x reference)
//
#include <hip/hip_runtime.h>

#define TM 64
#define NTHREADS 256
#define PAD 132

typedef __attribute__((ext_vector_type(8))) short short8;
typedef __attribute__((ext_vector_type(4))) float f32x4;

__device__ __forceinline__ short f2bf(float f) {
  union { float f; unsigned u; } uf; uf.f = f;
  unsigned r = uf.u + 0x7FFFu + ((uf.u >> 16) & 1u);   // RNE
  return (short)(r >> 16);
}
__device__ __forceinline__ float bf2f(short s) {
  union { unsigned u; float f; } uf; uf.u = ((unsigned)(unsigned short)s) << 16;
  return uf.f;
}
__device__ __forceinline__ short8 pack8(float4 a, float4 b) {
  short8 r;
  r[0] = f2bf(a.x); r[1] = f2bf(a.y); r[2] = f2bf(a.z); r[3] = f2bf(a.w);
  r[4] = f2bf(b.x); r[5] = f2bf(b.y); r[6] = f2bf(b.z); r[7] = f2bf(b.w);
  return r;
}

// ==================== MFMA projection (bf16 out, for qp) ====================

__global__ __launch_bounds__(512) void proj_mfma_h(
    const float* __restrict__ X, const short* __restrict__ Wb,
    const float* __restrict__ bias, short* __restrict__ Yh, int M, float scale) {
  __shared__ short Xb[8192];
  int t = threadIdx.x;
  int w = t >> 6, l = t & 63, g = l >> 4, c = l & 15;
  short8 wf[4];
#pragma unroll
  for (int kc = 0; kc < 4; ++kc)
    wf[kc] = *(const short8*)(Wb + (w * 16 + c) * 128 + kc * 32 + g * 8);
  float4 b4 = *(const float4*)(bias + w * 16 + g * 4);

  for (int rb = blockIdx.x * 64; rb < M; rb += gridDim.x * 64) {
    {
      int r = t >> 3, q8 = t & 7;
      int row = rb + r; if (row >= M) row = M - 1;
      const float4* xs = (const float4*)(X + (size_t)row * 128 + q8 * 16);
      float4 x0 = xs[0], x1 = xs[1], x2 = xs[2], x3 = xs[3];
      int sw = (r & 7) << 4;
      *(short8*)((char*)Xb + r * 256 + ((q8 * 32) ^ sw)) = pack8(x0, x1);
      *(short8*)((char*)Xb + r * 256 + ((q8 * 32 + 16) ^ sw)) = pack8(x2, x3);
    }
    __syncthreads();
#pragma unroll
    for (int et = 0; et < 4; ++et) {
      int rl = et * 16 + c;
      f32x4 acc = {};
      int sw = (rl & 7) << 4;
#pragma unroll
      for (int kc = 0; kc < 4; ++kc) {
        short8 xb = *(const short8*)((char*)Xb + rl * 256 + ((kc * 64 + g * 16) ^ sw));
        acc = __builtin_amdgcn_mfma_f32_16x16x32_bf16(wf[kc], xb, acc, 0, 0, 0);
      }
      int row = rb + rl;
      if (row < M) {
        short4 o;
        o.x = f2bf((acc[0] + b4.x) * scale); o.y = f2bf((acc[1] + b4.y) * scale);
        o.z = f2bf((acc[2] + b4.z) * scale); o.w = f2bf((acc[3] + b4.w) * scale);
        *(short4*)(Yh + (size_t)row * 128 + w * 16 + g * 4) = o;
      }
    }
    __syncthreads();
  }
}

// ==================== MFMA projection (bf16 IN, f32 out — for out-proj) ====

__global__ __launch_bounds__(512) void proj_mfma_hin(
    const short* __restrict__ Xh, const short* __restrict__ Wb,
    const float* __restrict__ bias, float* __restrict__ Y, int M) {
  __shared__ short Xb[8192];
  int t = threadIdx.x;
  int w = t >> 6, l = t & 63, g = l >> 4, c = l & 15;
  short8 wf[4];
#pragma unroll
  for (int kc = 0; kc < 4; ++kc)
    wf[kc] = *(const short8*)(Wb + (w * 16 + c) * 128 + kc * 32 + g * 8);
  float4 b4 = *(const float4*)(bias + w * 16 + g * 4);

  for (int rb = blockIdx.x * 64; rb < M; rb += gridDim.x * 64) {
    {
      int r = t >> 3, q8 = t & 7;
      int row = rb + r; if (row >= M) row = M - 1;
      const short8* xs = (const short8*)(Xh + (size_t)row * 128 + q8 * 16);
      short8 a = xs[0], b = xs[1];
      int sw = (r & 7) << 4;
      *(short8*)((char*)Xb + r * 256 + ((q8 * 32) ^ sw)) = a;
      *(short8*)((char*)Xb + r * 256 + ((q8 * 32 + 16) ^ sw)) = b;
    }
    __syncthreads();
#pragma unroll
    for (int et = 0; et < 4; ++et) {
      int rl = et * 16 + c;
      f32x4 acc = {};
      int sw = (rl & 7) << 4;
#pragma unroll
      for (int kc = 0; kc < 4; ++kc) {
        short8 xb = *(const short8*)((char*)Xb + rl * 256 + ((kc * 64 + g * 16) ^ sw));
        acc = __builtin_amdgcn_mfma_f32_16x16x32_bf16(wf[kc], xb, acc, 0, 0, 0);
      }
      int row = rb + rl;
      if (row < M) {
        float4 o;
        o.x = acc[0] + b4.x; o.y = acc[1] + b4.y;
        o.z = acc[2] + b4.z; o.w = acc[3] + b4.w;
        *(float4*)(Y + (size_t)row * 128 + w * 16 + g * 4) = o;
      }
    }
    __syncthreads();
  }
}

// ==================== CSR build (rank-based; no separate perm pass) ====

__global__ __launch_bounds__(256) void rank_hist(const int* __restrict__ dst,
                                                 int* __restrict__ cnt,
                                                 int* __restrict__ rank, int E) {
  int e = blockIdx.x * 256 + threadIdx.x;
  if (e < E) rank[e] = atomicAdd(&cnt[dst[e]], 1);
}

__global__ __launch_bounds__(1024) void scan_part(const int* __restrict__ cnt,
                                                  int* __restrict__ part, int N) {
  __shared__ int ws[16];
  int t = threadIdx.x, i = blockIdx.x * 1024 + t;
  int v = (i < N) ? cnt[i] : 0;
#pragma unroll
  for (int d = 1; d < 64; d <<= 1) v += __shfl_xor(v, d);
  if ((t & 63) == 0) ws[t >> 6] = v;
  __syncthreads();
  if (t < 16) {
    int x = ws[t];
#pragma unroll
    for (int d = 1; d < 16; d <<= 1) x += __shfl_xor(x, d);
    if (t == 0) part[blockIdx.x] = x;
  }
}

__global__ __launch_bounds__(1024) void scan_final(const int* __restrict__ cnt,
                                                   const int* __restrict__ part,
                                                   int* __restrict__ rp, int N) {
  __shared__ int ws[16];
  __shared__ int wofs[16];
  __shared__ int base_sh;
  int t = threadIdx.x, i = blockIdx.x * 1024 + t;
  int lane = t & 63, wid = t >> 6;
  if (t < 64) {
    int v = 0;
    for (int j = t; j < blockIdx.x; j += 64) v += part[j];
#pragma unroll
    for (int d = 1; d < 64; d <<= 1) v += __shfl_xor(v, d);
    if (t == 0) base_sh = v;
  }
  int v = (i < N) ? cnt[i] : 0;
  int x = v;
#pragma unroll
  for (int d = 1; d < 64; d <<= 1) { int y = __shfl_up(x, d); if (lane >= d) x += y; }
  if (lane == 63) ws[wid] = x;
  __syncthreads();
  if (t == 0) {
    int s = 0;
#pragma unroll
    for (int k2 = 0; k2 < 16; ++k2) { int tmp = ws[k2]; wofs[k2] = s; s += tmp; }
  }
  __syncthreads();
  int incl = x + wofs[wid] + base_sh;
  int excl = incl - v;
  if (i < N) {
    rp[i] = excl;
    if (i == N - 1) rp[N] = incl;
  }
}

__global__ __launch_bounds__(256) void wprep4(
    const float* __restrict__ Wq, const float* __restrict__ Wk,
    const float* __restrict__ Wv, const float* __restrict__ Wo,
    short* __restrict__ wqb, short* __restrict__ wkb,
    short* __restrict__ wvb, short* __restrict__ wob) {
  int i = blockIdx.x * 256 + threadIdx.x;
  if (i < 16384) {
    wqb[i] = f2bf(Wq[i]); wkb[i] = f2bf(Wk[i]);
    wvb[i] = f2bf(Wv[i]); wob[i] = f2bf(Wo[i]);
  }
}

// ==================== fused edge kernel (r17-proven body, unchanged) ====

__global__ __launch_bounds__(512) void edge_mfma7(
    const float* __restrict__ K, const float* __restrict__ V,
    const int* __restrict__ eidx, const int* __restrict__ rank,
    const int* __restrict__ rp,
    const short* __restrict__ wkb, const short* __restrict__ wvb,
    const float* __restrict__ bk, const short* __restrict__ qpb,
    float* __restrict__ exb, short* __restrict__ wv, int E) {
  __shared__ short Kb[8192];
  __shared__ short Vb[8192];
  __shared__ float exs[512];
  __shared__ int sh_perm[64];
  int t = threadIdx.x;
  int w = t >> 6, l = t & 63, g = l >> 4, c = l & 15;
  float4 bk4 = *(const float4*)(bk + w * 16 + g * 4);
  const short* wkp = wkb + (w * 16 + c) * 128 + g * 8;
  const short* wvp = wvb + (w * 16 + c) * 128 + g * 8;
  const short* qpp = qpb + (size_t)(w * 16 + g * 4);

  int r = t >> 3, q8 = t & 7;                 // staging role
  int sw_st = (r & 7) << 4;
  int b0 = r * 256 + ((q8 * 32) ^ sw_st);
  int stride = gridDim.x * 64;
  int eb = blockIdx.x * 64;

  // ---- prologue: tile-0 K rows, slot, qvb (bf16, via transient dst) ----
  float4 k0, k1, k2, k3;
  short4 qvb[4];
  int prm_r;
  {
    int row0 = eb + r; if (row0 >= E) row0 = E - 1;
    const float4* ks = (const float4*)(K + (size_t)row0 * 128 + q8 * 16);
    k0 = ks[0]; k1 = ks[1]; k2 = ks[2]; k3 = ks[3];
    prm_r = rp[eidx[row0]] + rank[row0];
#pragma unroll
    for (int et = 0; et < 4; ++et) {
      int e = eb + et * 16 + c; if (e >= E) e = E - 1;
      qvb[et] = *(const short4*)(qpp + (size_t)eidx[e] * 128);
    }
  }

  for (; eb < E; eb += stride) {
    int ebn = eb + stride;
    bool hn = ebn < E;

    __syncthreads();                    // buffers free (prev writeout done)
    *(short8*)((char*)Kb + b0) = pack8(k0, k1);
    *(short8*)((char*)Kb + (b0 ^ 16)) = pack8(k2, k3);
    if (q8 == 0) sh_perm[r] = prm_r;
    short8 wK[4];
#pragma unroll
    for (int kc = 0; kc < 4; ++kc)
      wK[kc] = *(const short8*)(wkp + kc * 32);
    float4 v0, v1, v2, v3;
    {
      int rowv = eb + r; if (rowv >= E) rowv = E - 1;
      const float4* vs = (const float4*)(V + (size_t)rowv * 128 + q8 * 16);
      v0 = vs[0]; v1 = vs[1]; v2 = vs[2]; v3 = vs[3];
    }
    __syncthreads();                    // Kb + sh_perm ready

    // ---- K phase: proj + score + exp ----
    float ex[4];
#pragma unroll
    for (int et = 0; et < 4; ++et) {
      int eloc = et * 16 + c;
      int swr = (eloc & 7) << 4;
      f32x4 acc = {};
#pragma unroll
      for (int kc = 0; kc < 4; ++kc) {
        short8 xb = *(const short8*)((char*)Kb + eloc * 256 + ((kc * 64 + g * 16) ^ swr));
        acc = __builtin_amdgcn_mfma_f32_16x16x32_bf16(wK[kc], xb, acc, 0, 0, 0);
      }
      float s = (acc[0] + bk4.x) * bf2f(qvb[et].x) + (acc[1] + bk4.y) * bf2f(qvb[et].y) +
                (acc[2] + bk4.z) * bf2f(qvb[et].z) + (acc[3] + bk4.w) * bf2f(qvb[et].w);
      s += __shfl_xor(s, 16);
      s += __shfl_xor(s, 32);
      ex[et] = __expf(s);
      if (g == 0) exs[eloc * 8 + w] = ex[et];
    }

    // stage V regs -> LDS; stream wV; issue next-tile K/slot/qvb loads
    *(short8*)((char*)Vb + b0) = pack8(v0, v1);
    *(short8*)((char*)Vb + (b0 ^ 16)) = pack8(v2, v3);
    short8 wV[4];
#pragma unroll
    for (int kc = 0; kc < 4; ++kc)
      wV[kc] = *(const short8*)(wvp + kc * 32);
    int prm_rn = 0;
    if (hn) {
      int rowk = ebn + r; if (rowk >= E) rowk = E - 1;
      const float4* ks = (const float4*)(K + (size_t)rowk * 128 + q8 * 16);
      k0 = ks[0]; k1 = ks[1]; k2 = ks[2]; k3 = ks[3];
      prm_rn = rp[eidx[rowk]] + rank[rowk];
#pragma unroll
      for (int et = 0; et < 4; ++et) {
        int e = ebn + et * 16 + c; if (e >= E) e = E - 1;
        qvb[et] = *(const short4*)(qpp + (size_t)eidx[e] * 128);
      }
    }
    __syncthreads();                    // Vb ready, Kb reads done

    // ---- V phase: proj + weight, repack into Kb ----
#pragma unroll
    for (int et = 0; et < 4; ++et) {
      int eloc = et * 16 + c;
      int swr = (eloc & 7) << 4;
      f32x4 acc = {};
#pragma unroll
      for (int kc = 0; kc < 4; ++kc) {
        short8 xb = *(const short8*)((char*)Vb + eloc * 256 + ((kc * 64 + g * 16) ^ swr));
        acc = __builtin_amdgcn_mfma_f32_16x16x32_bf16(wV[kc], xb, acc, 0, 0, 0);
      }
      short4 sv;
      sv.x = f2bf(acc[0] * ex[et]); sv.y = f2bf(acc[1] * ex[et]);
      sv.z = f2bf(acc[2] * ex[et]); sv.w = f2bf(acc[3] * ex[et]);
      *(short4*)((char*)Kb + eloc * 256 + ((w * 32 + g * 8) ^ swr)) = sv;
    }
    prm_r = prm_rn;
    __syncthreads();                    // repack done

    // ---- CSR-slot writeout: wv rows (256B) + exb rows (32B) ----
    {
      int row = eb + r;
      if (row < E) {
        int slot = sh_perm[r];
        short8 a = *(const short8*)((char*)Kb + r * 256 + ((q8 * 32) ^ sw_st));
        short8 b = *(const short8*)((char*)Kb + r * 256 + ((q8 * 32 + 16) ^ sw_st));
        *(short8*)(wv + (size_t)slot * 128 + q8 * 16) = a;
        *(short8*)(wv + (size_t)slot * 128 + q8 * 16 + 8) = b;
      }
      if (t < 128) {
        int r2 = t >> 1, half = t & 1;
        if (eb + r2 < E) {
          int slot2 = sh_perm[r2];
          *(float4*)(exb + (size_t)slot2 * 8 + half * 4) =
              *(const float4*)(&exs[r2 * 8 + half * 4]);
        }
      }
    }
  }
}

// ==================== pull: streaming segmented sum -> bf16 aggr ====

__global__ __launch_bounds__(256) void pull3(
    const short* __restrict__ wv, const float* __restrict__ exb,
    const int* __restrict__ rp, const float* __restrict__ bv,
    short* __restrict__ aggrh, int N) {
  int w = threadIdx.x >> 6, l = threadIdx.x & 63;
  int n = blockIdx.x * 4 + w;
  if (n >= N) return;
  int beg = rp[n], end = rp[n + 1];
  int h = l >> 3;
  float a0 = 0.f, a1 = 0.f, s = 0.f;
  int j = beg;
  for (; j + 3 < end; j += 4) {
    unsigned u0 = *(const unsigned*)(wv + (size_t)j * 128 + l * 2);
    unsigned u1 = *(const unsigned*)(wv + (size_t)(j + 1) * 128 + l * 2);
    unsigned u2 = *(const unsigned*)(wv + (size_t)(j + 2) * 128 + l * 2);
    unsigned u3 = *(const unsigned*)(wv + (size_t)(j + 3) * 128 + l * 2);
    float s0 = exb[(size_t)j * 8 + h],       s1 = exb[(size_t)(j + 1) * 8 + h];
    float s2 = exb[(size_t)(j + 2) * 8 + h], s3 = exb[(size_t)(j + 3) * 8 + h];
    a0 += bf2f((short)(u0 & 0xFFFFu)) + bf2f((short)(u1 & 0xFFFFu)) +
          bf2f((short)(u2 & 0xFFFFu)) + bf2f((short)(u3 & 0xFFFFu));
    a1 += bf2f((short)(u0 >> 16)) + bf2f((short)(u1 >> 16)) +
          bf2f((short)(u2 >> 16)) + bf2f((short)(u3 >> 16));
    s += s0 + s1 + s2 + s3;
  }
  for (; j < end; ++j) {
    unsigned u0 = *(const unsigned*)(wv + (size_t)j * 128 + l * 2);
    s += exb[(size_t)j * 8 + h];
    a0 += bf2f((short)(u0 & 0xFFFFu));
    a1 += bf2f((short)(u0 >> 16));
  }
  float x0, x1;
  if (end > beg) {
    float inv = 1.f / (s + 1e-16f);
    float2 bvv = *(const float2*)(bv + l * 2);
    x0 = a0 * inv + bvv.x; x1 = a1 * inv + bvv.y;
  } else {
    x0 = 0.f; x1 = 0.f;
  }
  unsigned pk = ((unsigned)(unsigned short)f2bf(x1) << 16) |
                (unsigned short)f2bf(x0);
  *(unsigned*)(aggrh + (size_t)n * 128 + l * 2) = pk;
}

// ==================== fallback path (round-2 proven f32 kernels) ====================

__device__ __forceinline__ void stage_x(float (*Xs)[PAD], const float* __restrict__ X,
                                        int rowbase, int M, int t) {
#pragma unroll
  for (int i = 0; i < 8; ++i) {
    int idx = t + NTHREADS * i;
    int r = idx >> 5, q = idx & 31;
    int row = rowbase + r;
    if (row >= M) row = M - 1;
    const float4 v = *(const float4*)(X + (size_t)row * 128 + q * 4);
    *(float4*)(&Xs[r][q * 4]) = v;
  }
}

__device__ __forceinline__ void gemm_tile(const float (*Xs)[PAD], float (*WT)[PAD],
                                          const float* __restrict__ W,
                                          float acc[8][4], int r0, int c0, int t) {
#pragma unroll 1
  for (int kk = 0; kk < 128; kk += 32) {
    {
      int j = t >> 1, half = t & 1;
      const float* src = W + j * 128 + kk + half * 16;
      float4 a = *(const float4*)(src);
      float4 b = *(const float4*)(src + 4);
      float4 c = *(const float4*)(src + 8);
      float4 d = *(const float4*)(src + 12);
      int cb = half * 16;
      WT[cb + 0][j] = a.x;  WT[cb + 1][j] = a.y;  WT[cb + 2][j] = a.z;  WT[cb + 3][j] = a.w;
      WT[cb + 4][j] = b.x;  WT[cb + 5][j] = b.y;  WT[cb + 6][j] = b.z;  WT[cb + 7][j] = b.w;
      WT[cb + 8][j] = c.x;  WT[cb + 9][j] = c.y;  WT[cb + 10][j] = c.z; WT[cb + 11][j] = c.w;
      WT[cb + 12][j] = d.x; WT[cb + 13][j] = d.y; WT[cb + 14][j] = d.z; WT[cb + 15][j] = d.w;
    }
    __syncthreads();
#pragma unroll
    for (int c2 = 0; c2 < 16; ++c2) {
      float4 wa = *(const float4*)(&WT[2 * c2][c0]);
      float4 wb = *(const float4*)(&WT[2 * c2 + 1][c0]);
#pragma unroll
      for (int i = 0; i < 8; ++i) {
        float2 xv = *(const float2*)(&Xs[r0 + i][kk + 2 * c2]);
        acc[i][0] = fmaf(xv.x, wa.x, acc[i][0]);
        acc[i][1] = fmaf(xv.x, wa.y, acc[i][1]);
        acc[i][2] = fmaf(xv.x, wa.z, acc[i][2]);
        acc[i][3] = fmaf(xv.x, wa.w, acc[i][3]);
        acc[i][0] = fmaf(xv.y, wb.x, acc[i][0]);
        acc[i][1] = fmaf(xv.y, wb.y, acc[i][1]);
        acc[i][2] = fmaf(xv.y, wb.z, acc[i][2]);
        acc[i][3] = fmaf(xv.y, wb.w, acc[i][3]);
      }
    }
    __syncthreads();
  }
}

__global__ __launch_bounds__(NTHREADS) void proj_kernel(
    const float* __restrict__ X, const float* __restrict__ W,
    const float* __restrict__ b, float* __restrict__ Y, int M) {
  __shared__ float Xs[TM][PAD];
  __shared__ float WT[32][PAD];
  int t = threadIdx.x;
  int B0 = blockIdx.x * TM;
  stage_x(Xs, X, B0, M, t);
  __syncthreads();
  int r0 = (t >> 5) * 8, m = t & 31, c0 = m * 4;
  float acc[8][4] = {};
  gemm_tile(Xs, WT, W, acc, r0, c0, t);
  float4 bv = ((const float4*)b)[m];
#pragma unroll
  for (int i = 0; i < 8; ++i) {
    int row = B0 + r0 + i;
    if (row < M) {
      float4 o;
      o.x = acc[i][0] + bv.x; o.y = acc[i][1] + bv.y;
      o.z = acc[i][2] + bv.z; o.w = acc[i][3] + bv.w;
      *(float4*)(Y + (size_t)row * 128 + c0) = o;
    }
  }
}

__global__ __launch_bounds__(NTHREADS) void edge_kernel(
    const float* __restrict__ Kin, const float* __restrict__ Vin,
    const int* __restrict__ eidx,
    const float* __restrict__ Wk, const float* __restrict__ bk,
    const float* __restrict__ Wv, const float* __restrict__ bv,
    const float* __restrict__ qp, float* __restrict__ s_sum,
    float* __restrict__ aggr, int E) {
  __shared__ float Xs[TM][PAD];
  __shared__ float WT[32][PAD];
  __shared__ int dsts[TM];
  int t = threadIdx.x;
  int e0 = blockIdx.x * TM;
  if (t < TM) {
    int idx = e0 + t;
    if (idx >= E) idx = E - 1;
    dsts[t] = eidx[idx];
  }
  stage_x(Xs, Kin, e0, E, t);
  __syncthreads();
  int r0 = (t >> 5) * 8, m = t & 31, c0 = m * 4;
  int h = m >> 2;
  float acc[8][4] = {};
  gemm_tile(Xs, WT, Wk, acc, r0, c0, t);
  float4 bkv = ((const float4*)bk)[m];
  float ex[8];
#pragma unroll
  for (int i = 0; i < 8; ++i) {
    int r = r0 + i;
    const float4 qv = *(const float4*)(qp + (size_t)dsts[r] * 128 + c0);
    float p = (acc[i][0] + bkv.x) * qv.x + (acc[i][1] + bkv.y) * qv.y +
              (acc[i][2] + bkv.z) * qv.z + (acc[i][3] + bkv.w) * qv.w;
    p += __shfl_xor(p, 1);
    p += __shfl_xor(p, 2);
    float e = __expf(p * 0.25f);
    ex[i] = e;
    if ((m & 3) == 0 && (e0 + r) < E)
      atomicAdd(&s_sum[(size_t)dsts[r] * 8 + h], e);
  }
  __syncthreads();
  stage_x(Xs, Vin, e0, E, t);
  __syncthreads();
#pragma unroll
  for (int i = 0; i < 8; ++i)
#pragma unroll
    for (int j = 0; j < 4; ++j) acc[i][j] = 0.f;
  gemm_tile(Xs, WT, Wv, acc, r0, c0, t);
  float4 bvv = ((const float4*)bv)[m];
#pragma unroll
  for (int i = 0; i < 8; ++i) {
    int r = r0 + i;
    if ((e0 + r) < E) {
      size_t base = (size_t)dsts[r] * 128 + c0;
      atomicAdd(&aggr[base + 0], (acc[i][0] + bvv.x) * ex[i]);
      atomicAdd(&aggr[base + 1], (acc[i][1] + bvv.y) * ex[i]);
      atomicAdd(&aggr[base + 2], (acc[i][2] + bvv.z) * ex[i]);
      atomicAdd(&aggr[base + 3], (acc[i][3] + bvv.w) * ex[i]);
    }
  }
}

__global__ __launch_bounds__(NTHREADS) void out_kernel(
    const float* __restrict__ aggr, const float* __restrict__ s_sum,
    const float* __restrict__ W, const float* __restrict__ b,
    float* __restrict__ Y, int M) {
  __shared__ float Xs[TM][PAD];
  __shared__ float WT[32][PAD];
  int t = threadIdx.x;
  int B0 = blockIdx.x * TM;
#pragma unroll
  for (int i = 0; i < 8; ++i) {
    int idx = t + NTHREADS * i;
    int r = idx >> 5, q = idx & 31;
    int row = B0 + r;
    if (row >= M) row = M - 1;
    float4 v = *(const float4*)(aggr + (size_t)row * 128 + q * 4);
    float inv = 1.0f / (s_sum[(size_t)row * 8 + (q >> 2)] + 1e-16f);
    v.x *= inv; v.y *= inv; v.z *= inv; v.w *= inv;
    *(float4*)(&Xs[r][q * 4]) = v;
  }
  __syncthreads();
  int r0 = (t >> 5) * 8, m = t & 31, c0 = m * 4;
  float acc[8][4] = {};
  gemm_tile(Xs, WT, W, acc, r0, c0, t);
  float4 bv = ((const float4*)b)[m];
#pragma unroll
  for (int i = 0; i < 8; ++i) {
    int row = B0 + r0 + i;
    if (row < M) {
      float4 o;
      o.x = acc[i][0] + bv.x; o.y = acc[i][1] + bv.y;
      o.z = acc[i][2] + bv.z; o.w = acc[i][3] + bv.w;
      *(float4*)(Y + (size_t)row * 128 + c0) = o;
    }
  }
}

// ==================== launch ====================

extern "C" void kernel_launch(void* const* d_in, const int* in_sizes, int n_in,
                              void* d_out, int out_size, void* d_ws, size_t ws_size,
                              hipStream_t stream) {
  const float* q_nodes = (const float*)d_in[0];
  const float* k_edges = (const float*)d_in[1];
  const float* v_edges = (const float*)d_in[2];
  const int* eidx = (const int*)d_in[3];
  const float* Wq = (const float*)d_in[4];
  const float* bq = (const float*)d_in[5];
  const float* Wk = (const float*)d_in[6];
  const float* bk = (const float*)d_in[7];
  const float* Wv = (const float*)d_in[8];
  const float* bv = (const float*)d_in[9];
  const float* Wo = (const float*)d_in[10];
  const float* bo = (const float*)d_in[11];

  int N = in_sizes[0] / 128;
  int E = in_sizes[1] / 128;
  int P = (N + 1023) / 1024;

  size_t off = 0;
  auto alloc = [&](size_t b) { size_t o = off; off += (b + 255) & ~(size_t)255; return o; };
  size_t o_qpb  = alloc((size_t)N * 128 * 2);
  size_t o_agh  = alloc((size_t)N * 128 * 2);
  size_t o_exb  = alloc((size_t)E * 8 * 4);
  size_t o_rp   = alloc(((size_t)N + 1) * 4);
  size_t o_cnt  = alloc((size_t)N * 4);
  size_t o_rank = alloc((size_t)E * 4);
  size_t o_part = alloc((size_t)(P + 1) * 4);
  size_t o_wqb  = alloc((size_t)16384 * 2);
  size_t o_wkb  = alloc((size_t)16384 * 2);
  size_t o_wvb  = alloc((size_t)16384 * 2);
  size_t o_wob  = alloc((size_t)16384 * 2);
  size_t o_wv   = alloc((size_t)E * 128 * 2);

  if (off <= ws_size) {
    char* base = (char*)d_ws;
    short* qpb   = (short*)(base + o_qpb);
    short* aggrh = (short*)(base + o_agh);
    float* exb   = (float*)(base + o_exb);
    int*   rp    = (int*)(base + o_rp);
    int*   cnt   = (int*)(base + o_cnt);
    int*   rank  = (int*)(base + o_rank);
    int*   part  = (int*)(base + o_part);
    short* wqb   = (short*)(base + o_wqb);
    short* wkb   = (short*)(base + o_wkb);
    short* wvb   = (short*)(base + o_wvb);
    short* wob   = (short*)(base + o_wob);
    short* wvbuf = (short*)(base + o_wv);

    hipMemsetAsync(cnt, 0, (size_t)N * 4, stream);
    wprep4<<<64, 256, 0, stream>>>(Wq, Wk, Wv, Wo, wqb, wkb, wvb, wob);
    // qp in bf16, pre-scaled by SCALE=0.25
    proj_mfma_h<<<(N + 63) / 64, 512, 0, stream>>>(q_nodes, wqb, bq, qpb, N, 0.25f);
    rank_hist<<<(E + 255) / 256, 256, 0, stream>>>(eidx, cnt, rank, E);
    scan_part<<<P, 1024, 0, stream>>>(cnt, part, N);
    scan_final<<<P, 1024, 0, stream>>>(cnt, part, rp, N);

    int eblk = (E + 63) / 64; if (eblk > 2048) eblk = 2048;
    edge_mfma7<<<eblk, 512, 0, stream>>>(k_edges, v_edges, eidx, rank, rp, wkb, wvb,
                                         bk, qpb, exb, wvbuf, E);
    pull3<<<(N + 3) / 4, 256, 0, stream>>>(wvbuf, exb, rp, bv, aggrh, N);
    proj_mfma_hin<<<(N + 63) / 64, 512, 0, stream>>>(aggrh, wob, bo, (float*)d_out, N);
  } else {
    float* q_proj = (float*)d_ws;
    float* s_sum  = q_proj + (size_t)N * 128;
    float* aggr   = s_sum + (size_t)N * 8;
    hipMemsetAsync(s_sum, 0, (size_t)N * 136 * sizeof(float), stream);
    int nblk = (N + TM - 1) / TM;
    int eblk = (E + TM - 1) / TM;
    proj_kernel<<<nblk, NTHREADS, 0, stream>>>(q_nodes, Wq, bq, q_proj, N);
    edge_kernel<<<eblk, NTHREADS, 0, stream>>>(k_edges, v_edges, eidx, Wk, bk, Wv, bv,
                                               q_proj, s_sum, aggr, E);
    out_kernel<<<nblk, NTHREADS, 0, stream>>>(aggr, s_sum, Wo, bo, (float*)d_out, N);
  }
}

// Round 19
// 378.203 us; speedup vs baseline: 1.0135x; 1.0135x over previous
//
#include <hip/hip_runtime.h>

#define TM 64
#define NTHREADS 256
#define PAD 132

typedef __attribute__((ext_vector_type(8))) short short8;
typedef __attribute__((ext_vector_type(4))) float f32x4;

__device__ __forceinline__ short f2bf(float f) {
  union { float f; unsigned u; } uf; uf.f = f;
  unsigned r = uf.u + 0x7FFFu + ((uf.u >> 16) & 1u);   // RNE
  return (short)(r >> 16);
}
__device__ __forceinline__ float bf2f(short s) {
  union { unsigned u; float f; } uf; uf.u = ((unsigned)(unsigned short)s) << 16;
  return uf.f;
}
__device__ __forceinline__ short8 pack8(float4 a, float4 b) {
  short8 r;
  r[0] = f2bf(a.x); r[1] = f2bf(a.y); r[2] = f2bf(a.z); r[3] = f2bf(a.w);
  r[4] = f2bf(b.x); r[5] = f2bf(b.y); r[6] = f2bf(b.z); r[7] = f2bf(b.w);
  return r;
}

// ==================== MFMA projection (bf16 out, for qp) ====================

__global__ __launch_bounds__(512) void proj_mfma_h(
    const float* __restrict__ X, const short* __restrict__ Wb,
    const float* __restrict__ bias, short* __restrict__ Yh, int M, float scale) {
  __shared__ short Xb[8192];
  int t = threadIdx.x;
  int w = t >> 6, l = t & 63, g = l >> 4, c = l & 15;
  short8 wf[4];
#pragma unroll
  for (int kc = 0; kc < 4; ++kc)
    wf[kc] = *(const short8*)(Wb + (w * 16 + c) * 128 + kc * 32 + g * 8);
  float4 b4 = *(const float4*)(bias + w * 16 + g * 4);

  for (int rb = blockIdx.x * 64; rb < M; rb += gridDim.x * 64) {
    {
      int r = t >> 3, q8 = t & 7;
      int row = rb + r; if (row >= M) row = M - 1;
      const float4* xs = (const float4*)(X + (size_t)row * 128 + q8 * 16);
      float4 x0 = xs[0], x1 = xs[1], x2 = xs[2], x3 = xs[3];
      int sw = (r & 7) << 4;
      *(short8*)((char*)Xb + r * 256 + ((q8 * 32) ^ sw)) = pack8(x0, x1);
      *(short8*)((char*)Xb + r * 256 + ((q8 * 32 + 16) ^ sw)) = pack8(x2, x3);
    }
    __syncthreads();
#pragma unroll
    for (int et = 0; et < 4; ++et) {
      int rl = et * 16 + c;
      f32x4 acc = {};
      int sw = (rl & 7) << 4;
#pragma unroll
      for (int kc = 0; kc < 4; ++kc) {
        short8 xb = *(const short8*)((char*)Xb + rl * 256 + ((kc * 64 + g * 16) ^ sw));
        acc = __builtin_amdgcn_mfma_f32_16x16x32_bf16(wf[kc], xb, acc, 0, 0, 0);
      }
      int row = rb + rl;
      if (row < M) {
        short4 o;
        o.x = f2bf((acc[0] + b4.x) * scale); o.y = f2bf((acc[1] + b4.y) * scale);
        o.z = f2bf((acc[2] + b4.z) * scale); o.w = f2bf((acc[3] + b4.w) * scale);
        *(short4*)(Yh + (size_t)row * 128 + w * 16 + g * 4) = o;
      }
    }
    __syncthreads();
  }
}

// ==================== MFMA projection (bf16 IN, f32 out — for out-proj) ====

__global__ __launch_bounds__(512) void proj_mfma_hin(
    const short* __restrict__ Xh, const short* __restrict__ Wb,
    const float* __restrict__ bias, float* __restrict__ Y, int M) {
  __shared__ short Xb[8192];
  int t = threadIdx.x;
  int w = t >> 6, l = t & 63, g = l >> 4, c = l & 15;
  short8 wf[4];
#pragma unroll
  for (int kc = 0; kc < 4; ++kc)
    wf[kc] = *(const short8*)(Wb + (w * 16 + c) * 128 + kc * 32 + g * 8);
  float4 b4 = *(const float4*)(bias + w * 16 + g * 4);

  for (int rb = blockIdx.x * 64; rb < M; rb += gridDim.x * 64) {
    {
      int r = t >> 3, q8 = t & 7;
      int row = rb + r; if (row >= M) row = M - 1;
      const short8* xs = (const short8*)(Xh + (size_t)row * 128 + q8 * 16);
      short8 a = xs[0], b = xs[1];
      int sw = (r & 7) << 4;
      *(short8*)((char*)Xb + r * 256 + ((q8 * 32) ^ sw)) = a;
      *(short8*)((char*)Xb + r * 256 + ((q8 * 32 + 16) ^ sw)) = b;
    }
    __syncthreads();
#pragma unroll
    for (int et = 0; et < 4; ++et) {
      int rl = et * 16 + c;
      f32x4 acc = {};
      int sw = (rl & 7) << 4;
#pragma unroll
      for (int kc = 0; kc < 4; ++kc) {
        short8 xb = *(const short8*)((char*)Xb + rl * 256 + ((kc * 64 + g * 16) ^ sw));
        acc = __builtin_amdgcn_mfma_f32_16x16x32_bf16(wf[kc], xb, acc, 0, 0, 0);
      }
      int row = rb + rl;
      if (row < M) {
        float4 o;
        o.x = acc[0] + b4.x; o.y = acc[1] + b4.y;
        o.z = acc[2] + b4.z; o.w = acc[3] + b4.w;
        *(float4*)(Y + (size_t)row * 128 + w * 16 + g * 4) = o;
      }
    }
    __syncthreads();
  }
}

// ==================== CSR build (rank-based; no separate perm pass) ====

__global__ __launch_bounds__(256) void rank_hist(const int* __restrict__ dst,
                                                 int* __restrict__ cnt,
                                                 int* __restrict__ rank, int E) {
  int e = blockIdx.x * 256 + threadIdx.x;
  if (e < E) rank[e] = atomicAdd(&cnt[dst[e]], 1);
}

__global__ __launch_bounds__(1024) void scan_part(const int* __restrict__ cnt,
                                                  int* __restrict__ part, int N) {
  __shared__ int ws[16];
  int t = threadIdx.x, i = blockIdx.x * 1024 + t;
  int v = (i < N) ? cnt[i] : 0;
#pragma unroll
  for (int d = 1; d < 64; d <<= 1) v += __shfl_xor(v, d);
  if ((t & 63) == 0) ws[t >> 6] = v;
  __syncthreads();
  if (t < 16) {
    int x = ws[t];
#pragma unroll
    for (int d = 1; d < 16; d <<= 1) x += __shfl_xor(x, d);
    if (t == 0) part[blockIdx.x] = x;
  }
}

__global__ __launch_bounds__(1024) void scan_final(const int* __restrict__ cnt,
                                                   const int* __restrict__ part,
                                                   int* __restrict__ rp, int N) {
  __shared__ int ws[16];
  __shared__ int wofs[16];
  __shared__ int base_sh;
  int t = threadIdx.x, i = blockIdx.x * 1024 + t;
  int lane = t & 63, wid = t >> 6;
  if (t < 64) {
    int v = 0;
    for (int j = t; j < blockIdx.x; j += 64) v += part[j];
#pragma unroll
    for (int d = 1; d < 64; d <<= 1) v += __shfl_xor(v, d);
    if (t == 0) base_sh = v;
  }
  int v = (i < N) ? cnt[i] : 0;
  int x = v;
#pragma unroll
  for (int d = 1; d < 64; d <<= 1) { int y = __shfl_up(x, d); if (lane >= d) x += y; }
  if (lane == 63) ws[wid] = x;
  __syncthreads();
  if (t == 0) {
    int s = 0;
#pragma unroll
    for (int k2 = 0; k2 < 16; ++k2) { int tmp = ws[k2]; wofs[k2] = s; s += tmp; }
  }
  __syncthreads();
  int incl = x + wofs[wid] + base_sh;
  int excl = incl - v;
  if (i < N) {
    rp[i] = excl;
    if (i == N - 1) rp[N] = incl;
  }
}

__global__ __launch_bounds__(256) void wprep4(
    const float* __restrict__ Wq, const float* __restrict__ Wk,
    const float* __restrict__ Wv, const float* __restrict__ Wo,
    short* __restrict__ wqb, short* __restrict__ wkb,
    short* __restrict__ wvb, short* __restrict__ wob) {
  int i = blockIdx.x * 256 + threadIdx.x;
  if (i < 16384) {
    wqb[i] = f2bf(Wq[i]); wkb[i] = f2bf(Wk[i]);
    wvb[i] = f2bf(Wv[i]); wob[i] = f2bf(Wo[i]);
  }
}

// ==================== fused edge kernel (r17-proven body, grid cap 1024) ====

__global__ __launch_bounds__(512) void edge_mfma7(
    const float* __restrict__ K, const float* __restrict__ V,
    const int* __restrict__ eidx, const int* __restrict__ rank,
    const int* __restrict__ rp,
    const short* __restrict__ wkb, const short* __restrict__ wvb,
    const float* __restrict__ bk, const short* __restrict__ qpb,
    float* __restrict__ exb, short* __restrict__ wv, int E) {
  __shared__ short Kb[8192];
  __shared__ short Vb[8192];
  __shared__ float exs[512];
  __shared__ int sh_perm[64];
  int t = threadIdx.x;
  int w = t >> 6, l = t & 63, g = l >> 4, c = l & 15;
  float4 bk4 = *(const float4*)(bk + w * 16 + g * 4);
  const short* wkp = wkb + (w * 16 + c) * 128 + g * 8;
  const short* wvp = wvb + (w * 16 + c) * 128 + g * 8;
  const short* qpp = qpb + (size_t)(w * 16 + g * 4);

  int r = t >> 3, q8 = t & 7;                 // staging role
  int sw_st = (r & 7) << 4;
  int b0 = r * 256 + ((q8 * 32) ^ sw_st);
  int stride = gridDim.x * 64;
  int eb = blockIdx.x * 64;

  // ---- prologue: tile-0 K rows, slot, qvb (bf16, via transient dst) ----
  float4 k0, k1, k2, k3;
  short4 qvb[4];
  int prm_r;
  {
    int row0 = eb + r; if (row0 >= E) row0 = E - 1;
    const float4* ks = (const float4*)(K + (size_t)row0 * 128 + q8 * 16);
    k0 = ks[0]; k1 = ks[1]; k2 = ks[2]; k3 = ks[3];
    prm_r = rp[eidx[row0]] + rank[row0];
#pragma unroll
    for (int et = 0; et < 4; ++et) {
      int e = eb + et * 16 + c; if (e >= E) e = E - 1;
      qvb[et] = *(const short4*)(qpp + (size_t)eidx[e] * 128);
    }
  }

  for (; eb < E; eb += stride) {
    int ebn = eb + stride;
    bool hn = ebn < E;

    __syncthreads();                    // buffers free (prev writeout done)
    *(short8*)((char*)Kb + b0) = pack8(k0, k1);
    *(short8*)((char*)Kb + (b0 ^ 16)) = pack8(k2, k3);
    if (q8 == 0) sh_perm[r] = prm_r;
    short8 wK[4];
#pragma unroll
    for (int kc = 0; kc < 4; ++kc)
      wK[kc] = *(const short8*)(wkp + kc * 32);
    float4 v0, v1, v2, v3;
    {
      int rowv = eb + r; if (rowv >= E) rowv = E - 1;
      const float4* vs = (const float4*)(V + (size_t)rowv * 128 + q8 * 16);
      v0 = vs[0]; v1 = vs[1]; v2 = vs[2]; v3 = vs[3];
    }
    __syncthreads();                    // Kb + sh_perm ready

    // ---- K phase: proj + score + exp ----
    float ex[4];
#pragma unroll
    for (int et = 0; et < 4; ++et) {
      int eloc = et * 16 + c;
      int swr = (eloc & 7) << 4;
      f32x4 acc = {};
#pragma unroll
      for (int kc = 0; kc < 4; ++kc) {
        short8 xb = *(const short8*)((char*)Kb + eloc * 256 + ((kc * 64 + g * 16) ^ swr));
        acc = __builtin_amdgcn_mfma_f32_16x16x32_bf16(wK[kc], xb, acc, 0, 0, 0);
      }
      float s = (acc[0] + bk4.x) * bf2f(qvb[et].x) + (acc[1] + bk4.y) * bf2f(qvb[et].y) +
                (acc[2] + bk4.z) * bf2f(qvb[et].z) + (acc[3] + bk4.w) * bf2f(qvb[et].w);
      s += __shfl_xor(s, 16);
      s += __shfl_xor(s, 32);
      ex[et] = __expf(s);
      if (g == 0) exs[eloc * 8 + w] = ex[et];
    }

    // stage V regs -> LDS; stream wV; issue next-tile K/slot/qvb loads
    *(short8*)((char*)Vb + b0) = pack8(v0, v1);
    *(short8*)((char*)Vb + (b0 ^ 16)) = pack8(v2, v3);
    short8 wV[4];
#pragma unroll
    for (int kc = 0; kc < 4; ++kc)
      wV[kc] = *(const short8*)(wvp + kc * 32);
    int prm_rn = 0;
    if (hn) {
      int rowk = ebn + r; if (rowk >= E) rowk = E - 1;
      const float4* ks = (const float4*)(K + (size_t)rowk * 128 + q8 * 16);
      k0 = ks[0]; k1 = ks[1]; k2 = ks[2]; k3 = ks[3];
      prm_rn = rp[eidx[rowk]] + rank[rowk];
#pragma unroll
      for (int et = 0; et < 4; ++et) {
        int e = ebn + et * 16 + c; if (e >= E) e = E - 1;
        qvb[et] = *(const short4*)(qpp + (size_t)eidx[e] * 128);
      }
    }
    __syncthreads();                    // Vb ready, Kb reads done

    // ---- V phase: proj + weight, repack into Kb ----
#pragma unroll
    for (int et = 0; et < 4; ++et) {
      int eloc = et * 16 + c;
      int swr = (eloc & 7) << 4;
      f32x4 acc = {};
#pragma unroll
      for (int kc = 0; kc < 4; ++kc) {
        short8 xb = *(const short8*)((char*)Vb + eloc * 256 + ((kc * 64 + g * 16) ^ swr));
        acc = __builtin_amdgcn_mfma_f32_16x16x32_bf16(wV[kc], xb, acc, 0, 0, 0);
      }
      short4 sv;
      sv.x = f2bf(acc[0] * ex[et]); sv.y = f2bf(acc[1] * ex[et]);
      sv.z = f2bf(acc[2] * ex[et]); sv.w = f2bf(acc[3] * ex[et]);
      *(short4*)((char*)Kb + eloc * 256 + ((w * 32 + g * 8) ^ swr)) = sv;
    }
    prm_r = prm_rn;
    __syncthreads();                    // repack done

    // ---- CSR-slot writeout: wv rows (256B) + exb rows (32B) ----
    {
      int row = eb + r;
      if (row < E) {
        int slot = sh_perm[r];
        short8 a = *(const short8*)((char*)Kb + r * 256 + ((q8 * 32) ^ sw_st));
        short8 b = *(const short8*)((char*)Kb + r * 256 + ((q8 * 32 + 16) ^ sw_st));
        *(short8*)(wv + (size_t)slot * 128 + q8 * 16) = a;
        *(short8*)(wv + (size_t)slot * 128 + q8 * 16 + 8) = b;
      }
      if (t < 128) {
        int r2 = t >> 1, half = t & 1;
        if (eb + r2 < E) {
          int slot2 = sh_perm[r2];
          *(float4*)(exb + (size_t)slot2 * 8 + half * 4) =
              *(const float4*)(&exs[r2 * 8 + half * 4]);
        }
      }
    }
  }
}

// ==================== pull: streaming segmented sum -> bf16 aggr ====

__global__ __launch_bounds__(256) void pull3(
    const short* __restrict__ wv, const float* __restrict__ exb,
    const int* __restrict__ rp, const float* __restrict__ bv,
    short* __restrict__ aggrh, int N) {
  int w = threadIdx.x >> 6, l = threadIdx.x & 63;
  int n = blockIdx.x * 4 + w;
  if (n >= N) return;
  int beg = rp[n], end = rp[n + 1];
  int h = l >> 3;
  float a0 = 0.f, a1 = 0.f, s = 0.f;
  int j = beg;
  for (; j + 3 < end; j += 4) {
    unsigned u0 = *(const unsigned*)(wv + (size_t)j * 128 + l * 2);
    unsigned u1 = *(const unsigned*)(wv + (size_t)(j + 1) * 128 + l * 2);
    unsigned u2 = *(const unsigned*)(wv + (size_t)(j + 2) * 128 + l * 2);
    unsigned u3 = *(const unsigned*)(wv + (size_t)(j + 3) * 128 + l * 2);
    float s0 = exb[(size_t)j * 8 + h],       s1 = exb[(size_t)(j + 1) * 8 + h];
    float s2 = exb[(size_t)(j + 2) * 8 + h], s3 = exb[(size_t)(j + 3) * 8 + h];
    a0 += bf2f((short)(u0 & 0xFFFFu)) + bf2f((short)(u1 & 0xFFFFu)) +
          bf2f((short)(u2 & 0xFFFFu)) + bf2f((short)(u3 & 0xFFFFu));
    a1 += bf2f((short)(u0 >> 16)) + bf2f((short)(u1 >> 16)) +
          bf2f((short)(u2 >> 16)) + bf2f((short)(u3 >> 16));
    s += s0 + s1 + s2 + s3;
  }
  for (; j < end; ++j) {
    unsigned u0 = *(const unsigned*)(wv + (size_t)j * 128 + l * 2);
    s += exb[(size_t)j * 8 + h];
    a0 += bf2f((short)(u0 & 0xFFFFu));
    a1 += bf2f((short)(u0 >> 16));
  }
  float x0, x1;
  if (end > beg) {
    float inv = 1.f / (s + 1e-16f);
    float2 bvv = *(const float2*)(bv + l * 2);
    x0 = a0 * inv + bvv.x; x1 = a1 * inv + bvv.y;
  } else {
    x0 = 0.f; x1 = 0.f;
  }
  unsigned pk = ((unsigned)(unsigned short)f2bf(x1) << 16) |
                (unsigned short)f2bf(x0);
  *(unsigned*)(aggrh + (size_t)n * 128 + l * 2) = pk;
}

// ==================== fallback path (round-2 proven f32 kernels) ====================

__device__ __forceinline__ void stage_x(float (*Xs)[PAD], const float* __restrict__ X,
                                        int rowbase, int M, int t) {
#pragma unroll
  for (int i = 0; i < 8; ++i) {
    int idx = t + NTHREADS * i;
    int r = idx >> 5, q = idx & 31;
    int row = rowbase + r;
    if (row >= M) row = M - 1;
    const float4 v = *(const float4*)(X + (size_t)row * 128 + q * 4);
    *(float4*)(&Xs[r][q * 4]) = v;
  }
}

__device__ __forceinline__ void gemm_tile(const float (*Xs)[PAD], float (*WT)[PAD],
                                          const float* __restrict__ W,
                                          float acc[8][4], int r0, int c0, int t) {
#pragma unroll 1
  for (int kk = 0; kk < 128; kk += 32) {
    {
      int j = t >> 1, half = t & 1;
      const float* src = W + j * 128 + kk + half * 16;
      float4 a = *(const float4*)(src);
      float4 b = *(const float4*)(src + 4);
      float4 c = *(const float4*)(src + 8);
      float4 d = *(const float4*)(src + 12);
      int cb = half * 16;
      WT[cb + 0][j] = a.x;  WT[cb + 1][j] = a.y;  WT[cb + 2][j] = a.z;  WT[cb + 3][j] = a.w;
      WT[cb + 4][j] = b.x;  WT[cb + 5][j] = b.y;  WT[cb + 6][j] = b.z;  WT[cb + 7][j] = b.w;
      WT[cb + 8][j] = c.x;  WT[cb + 9][j] = c.y;  WT[cb + 10][j] = c.z; WT[cb + 11][j] = c.w;
      WT[cb + 12][j] = d.x; WT[cb + 13][j] = d.y; WT[cb + 14][j] = d.z; WT[cb + 15][j] = d.w;
    }
    __syncthreads();
#pragma unroll
    for (int c2 = 0; c2 < 16; ++c2) {
      float4 wa = *(const float4*)(&WT[2 * c2][c0]);
      float4 wb = *(const float4*)(&WT[2 * c2 + 1][c0]);
#pragma unroll
      for (int i = 0; i < 8; ++i) {
        float2 xv = *(const float2*)(&Xs[r0 + i][kk + 2 * c2]);
        acc[i][0] = fmaf(xv.x, wa.x, acc[i][0]);
        acc[i][1] = fmaf(xv.x, wa.y, acc[i][1]);
        acc[i][2] = fmaf(xv.x, wa.z, acc[i][2]);
        acc[i][3] = fmaf(xv.x, wa.w, acc[i][3]);
        acc[i][0] = fmaf(xv.y, wb.x, acc[i][0]);
        acc[i][1] = fmaf(xv.y, wb.y, acc[i][1]);
        acc[i][2] = fmaf(xv.y, wb.z, acc[i][2]);
        acc[i][3] = fmaf(xv.y, wb.w, acc[i][3]);
      }
    }
    __syncthreads();
  }
}

__global__ __launch_bounds__(NTHREADS) void proj_kernel(
    const float* __restrict__ X, const float* __restrict__ W,
    const float* __restrict__ b, float* __restrict__ Y, int M) {
  __shared__ float Xs[TM][PAD];
  __shared__ float WT[32][PAD];
  int t = threadIdx.x;
  int B0 = blockIdx.x * TM;
  stage_x(Xs, X, B0, M, t);
  __syncthreads();
  int r0 = (t >> 5) * 8, m = t & 31, c0 = m * 4;
  float acc[8][4] = {};
  gemm_tile(Xs, WT, W, acc, r0, c0, t);
  float4 bv = ((const float4*)b)[m];
#pragma unroll
  for (int i = 0; i < 8; ++i) {
    int row = B0 + r0 + i;
    if (row < M) {
      float4 o;
      o.x = acc[i][0] + bv.x; o.y = acc[i][1] + bv.y;
      o.z = acc[i][2] + bv.z; o.w = acc[i][3] + bv.w;
      *(float4*)(Y + (size_t)row * 128 + c0) = o;
    }
  }
}

__global__ __launch_bounds__(NTHREADS) void edge_kernel(
    const float* __restrict__ Kin, const float* __restrict__ Vin,
    const int* __restrict__ eidx,
    const float* __restrict__ Wk, const float* __restrict__ bk,
    const float* __restrict__ Wv, const float* __restrict__ bv,
    const float* __restrict__ qp, float* __restrict__ s_sum,
    float* __restrict__ aggr, int E) {
  __shared__ float Xs[TM][PAD];
  __shared__ float WT[32][PAD];
  __shared__ int dsts[TM];
  int t = threadIdx.x;
  int e0 = blockIdx.x * TM;
  if (t < TM) {
    int idx = e0 + t;
    if (idx >= E) idx = E - 1;
    dsts[t] = eidx[idx];
  }
  stage_x(Xs, Kin, e0, E, t);
  __syncthreads();
  int r0 = (t >> 5) * 8, m = t & 31, c0 = m * 4;
  int h = m >> 2;
  float acc[8][4] = {};
  gemm_tile(Xs, WT, Wk, acc, r0, c0, t);
  float4 bkv = ((const float4*)bk)[m];
  float ex[8];
#pragma unroll
  for (int i = 0; i < 8; ++i) {
    int r = r0 + i;
    const float4 qv = *(const float4*)(qp + (size_t)dsts[r] * 128 + c0);
    float p = (acc[i][0] + bkv.x) * qv.x + (acc[i][1] + bkv.y) * qv.y +
              (acc[i][2] + bkv.z) * qv.z + (acc[i][3] + bkv.w) * qv.w;
    p += __shfl_xor(p, 1);
    p += __shfl_xor(p, 2);
    float e = __expf(p * 0.25f);
    ex[i] = e;
    if ((m & 3) == 0 && (e0 + r) < E)
      atomicAdd(&s_sum[(size_t)dsts[r] * 8 + h], e);
  }
  __syncthreads();
  stage_x(Xs, Vin, e0, E, t);
  __syncthreads();
#pragma unroll
  for (int i = 0; i < 8; ++i)
#pragma unroll
    for (int j = 0; j < 4; ++j) acc[i][j] = 0.f;
  gemm_tile(Xs, WT, Wv, acc, r0, c0, t);
  float4 bvv = ((const float4*)bv)[m];
#pragma unroll
  for (int i = 0; i < 8; ++i) {
    int r = r0 + i;
    if ((e0 + r) < E) {
      size_t base = (size_t)dsts[r] * 128 + c0;
      atomicAdd(&aggr[base + 0], (acc[i][0] + bvv.x) * ex[i]);
      atomicAdd(&aggr[base + 1], (acc[i][1] + bvv.y) * ex[i]);
      atomicAdd(&aggr[base + 2], (acc[i][2] + bvv.z) * ex[i]);
      atomicAdd(&aggr[base + 3], (acc[i][3] + bvv.w) * ex[i]);
    }
  }
}

__global__ __launch_bounds__(NTHREADS) void out_kernel(
    const float* __restrict__ aggr, const float* __restrict__ s_sum,
    const float* __restrict__ W, const float* __restrict__ b,
    float* __restrict__ Y, int M) {
  __shared__ float Xs[TM][PAD];
  __shared__ float WT[32][PAD];
  int t = threadIdx.x;
  int B0 = blockIdx.x * TM;
#pragma unroll
  for (int i = 0; i < 8; ++i) {
    int idx = t + NTHREADS * i;
    int r = idx >> 5, q = idx & 31;
    int row = B0 + r;
    if (row >= M) row = M - 1;
    float4 v = *(const float4*)(aggr + (size_t)row * 128 + q * 4);
    float inv = 1.0f / (s_sum[(size_t)row * 8 + (q >> 2)] + 1e-16f);
    v.x *= inv; v.y *= inv; v.z *= inv; v.w *= inv;
    *(float4*)(&Xs[r][q * 4]) = v;
  }
  __syncthreads();
  int r0 = (t >> 5) * 8, m = t & 31, c0 = m * 4;
  float acc[8][4] = {};
  gemm_tile(Xs, WT, W, acc, r0, c0, t);
  float4 bv = ((const float4*)b)[m];
#pragma unroll
  for (int i = 0; i < 8; ++i) {
    int row = B0 + r0 + i;
    if (row < M) {
      float4 o;
      o.x = acc[i][0] + bv.x; o.y = acc[i][1] + bv.y;
      o.z = acc[i][2] + bv.z; o.w = acc[i][3] + bv.w;
      *(float4*)(Y + (size_t)row * 128 + c0) = o;
    }
  }
}

// ==================== launch ====================

extern "C" void kernel_launch(void* const* d_in, const int* in_sizes, int n_in,
                              void* d_out, int out_size, void* d_ws, size_t ws_size,
                              hipStream_t stream) {
  const float* q_nodes = (const float*)d_in[0];
  const float* k_edges = (const float*)d_in[1];
  const float* v_edges = (const float*)d_in[2];
  const int* eidx = (const int*)d_in[3];
  const float* Wq = (const float*)d_in[4];
  const float* bq = (const float*)d_in[5];
  const float* Wk = (const float*)d_in[6];
  const float* bk = (const float*)d_in[7];
  const float* Wv = (const float*)d_in[8];
  const float* bv = (const float*)d_in[9];
  const float* Wo = (const float*)d_in[10];
  const float* bo = (const float*)d_in[11];

  int N = in_sizes[0] / 128;
  int E = in_sizes[1] / 128;
  int P = (N + 1023) / 1024;

  size_t off = 0;
  auto alloc = [&](size_t b) { size_t o = off; off += (b + 255) & ~(size_t)255; return o; };
  size_t o_qpb  = alloc((size_t)N * 128 * 2);
  size_t o_agh  = alloc((size_t)N * 128 * 2);
  size_t o_exb  = alloc((size_t)E * 8 * 4);
  size_t o_rp   = alloc(((size_t)N + 1) * 4);
  size_t o_cnt  = alloc((size_t)N * 4);
  size_t o_rank = alloc((size_t)E * 4);
  size_t o_part = alloc((size_t)(P + 1) * 4);
  size_t o_wqb  = alloc((size_t)16384 * 2);
  size_t o_wkb  = alloc((size_t)16384 * 2);
  size_t o_wvb  = alloc((size_t)16384 * 2);
  size_t o_wob  = alloc((size_t)16384 * 2);
  size_t o_wv   = alloc((size_t)E * 128 * 2);

  if (off <= ws_size) {
    char* base = (char*)d_ws;
    short* qpb   = (short*)(base + o_qpb);
    short* aggrh = (short*)(base + o_agh);
    float* exb   = (float*)(base + o_exb);
    int*   rp    = (int*)(base + o_rp);
    int*   cnt   = (int*)(base + o_cnt);
    int*   rank  = (int*)(base + o_rank);
    int*   part  = (int*)(base + o_part);
    short* wqb   = (short*)(base + o_wqb);
    short* wkb   = (short*)(base + o_wkb);
    short* wvb   = (short*)(base + o_wvb);
    short* wob   = (short*)(base + o_wob);
    short* wvbuf = (short*)(base + o_wv);

    hipMemsetAsync(cnt, 0, (size_t)N * 4, stream);
    wprep4<<<64, 256, 0, stream>>>(Wq, Wk, Wv, Wo, wqb, wkb, wvb, wob);
    // qp in bf16, pre-scaled by SCALE=0.25
    proj_mfma_h<<<(N + 63) / 64, 512, 0, stream>>>(q_nodes, wqb, bq, qpb, N, 0.25f);
    rank_hist<<<(E + 255) / 256, 256, 0, stream>>>(eidx, cnt, rank, E);
    scan_part<<<P, 1024, 0, stream>>>(cnt, part, N);
    scan_final<<<P, 1024, 0, stream>>>(cnt, part, rp, N);

    int eblk = (E + 63) / 64; if (eblk > 1024) eblk = 1024;
    edge_mfma7<<<eblk, 512, 0, stream>>>(k_edges, v_edges, eidx, rank, rp, wkb, wvb,
                                         bk, qpb, exb, wvbuf, E);
    pull3<<<(N + 3) / 4, 256, 0, stream>>>(wvbuf, exb, rp, bv, aggrh, N);
    proj_mfma_hin<<<(N + 63) / 64, 512, 0, stream>>>(aggrh, wob, bo, (float*)d_out, N);
  } else {
    float* q_proj = (float*)d_ws;
    float* s_sum  = q_proj + (size_t)N * 128;
    float* aggr   = s_sum + (size_t)N * 8;
    hipMemsetAsync(s_sum, 0, (size_t)N * 136 * sizeof(float), stream);
    int nblk = (N + TM - 1) / TM;
    int eblk = (E + TM - 1) / TM;
    proj_kernel<<<nblk, NTHREADS, 0, stream>>>(q_nodes, Wq, bq, q_proj, N);
    edge_kernel<<<eblk, NTHREADS, 0, stream>>>(k_edges, v_edges, eidx, Wk, bk, Wv, bv,
                                               q_proj, s_sum, aggr, E);
    out_kernel<<<nblk, NTHREADS, 0, stream>>>(aggr, s_sum, Wo, bo, (float*)d_out, N);
  }
}